// Round 10
// baseline (147.321 us; speedup 1.0000x reference)
//
#include <hip/hip_runtime.h>
#include <hip/hip_bf16.h>
#include <math.h>

typedef unsigned short u16;
typedef __attribute__((ext_vector_type(8))) short bf16x8;  // 8 bf16 (4 VGPRs)
typedef __attribute__((ext_vector_type(4))) float f32x4;   // 4 f32 acc

#define DEVI __device__ __forceinline__

constexpr int NV = 4;
constexpr int NB = 4096;
constexpr int ND = 1024;
constexpr int NH = 512;
constexpr int NC = 50;
constexpr int NSAMP = 10000;
constexpr int NCP = 64;  // padded C for MFMA N-dim

DEVI u16 to_bf16(float f) {
  union { float f; unsigned u; } v; v.f = f;
  unsigned r = v.u + 0x7fffu + ((v.u >> 16) & 1u);  // RNE
  return (u16)(r >> 16);
}

// compiler-native cast: emits v_cvt (pairs to v_cvt_pk_bf16_f32), RNE
DEVI u16 cvt_bf16(float f) {
  __hip_bfloat16 h = __float2bfloat16(f);
  return *reinterpret_cast<u16*>(&h);
}

// 8 f32 -> bf16x8 fragment, element-wise (stays in VGPRs)
DEVI bf16x8 cvt8(float4 a, float4 b) {
  bf16x8 r;
  r[0] = (short)cvt_bf16(a.x); r[1] = (short)cvt_bf16(a.y);
  r[2] = (short)cvt_bf16(a.z); r[3] = (short)cvt_bf16(a.w);
  r[4] = (short)cvt_bf16(b.x); r[5] = (short)cvt_bf16(b.y);
  r[6] = (short)cvt_bf16(b.z); r[7] = (short)cvt_bf16(b.w);
  return r;
}

DEVI float wsum(float x) {
#pragma unroll
  for (int m = 32; m > 0; m >>= 1) x += __shfl_xor(x, m, 64);
  return x;
}

// ------------------------------------------------- W1 (V,D,H) -> (V,H,D) bf16
__global__ __launch_bounds__(256) void k_transpose_w1(const float* __restrict__ W1,
                                                      u16* __restrict__ W1T) {
  __shared__ float tile[32][33];
  const int v = blockIdx.z;
  const int d0 = blockIdx.x * 32;
  const int h0 = blockIdx.y * 32;
  const float* src = W1 + (size_t)v * ND * NH;
  u16* dst = W1T + (size_t)v * NH * ND;
  const int tx = threadIdx.x, ty = threadIdx.y;  // (32, 8)
#pragma unroll
  for (int j = 0; j < 32; j += 8)
    tile[ty + j][tx] = src[(size_t)(d0 + ty + j) * NH + h0 + tx];
  __syncthreads();
#pragma unroll
  for (int j = 0; j < 32; j += 8)
    dst[(size_t)(h0 + ty + j) * ND + d0 + tx] = to_bf16(tile[tx][ty + j]);
}

// -------------------------------------- W2 (V,H,C) -> (V,64,H) bf16, zero-pad
__global__ __launch_bounds__(256) void k_prep_w2(const float* __restrict__ W2,
                                                 u16* __restrict__ W2T) {
  int i = blockIdx.x * blockDim.x + threadIdx.x;
  if (i >= NV * NCP * NH) return;
  int h = i % NH;
  int c = (i / NH) % NCP;
  int v = i / (NCP * NH);
  float val = (c < NC) ? W2[((size_t)v * NH + h) * NC + c] : 0.f;
  W2T[i] = to_bf16(val);
}

// --------------------------------------------------- GEMM1: h=relu(x@W1+b1)
// NO-LDS streaming GEMM: fragments loaded global->reg directly, 2-deep
// register double-buffer, zero barriers. A = x f32 (cvt in-reg), B = W1T bf16.
__global__ __launch_bounds__(256) void k_gemm1(const float* __restrict__ Xf,
                                               const u16* __restrict__ W1T,
                                               const float* __restrict__ b1,
                                               u16* __restrict__ Hb) {
  constexpr int BM = 128, BN = 128, BK = 32;
  const int v = blockIdx.z;
  const int m0 = blockIdx.x * BM;
  const int n0 = blockIdx.y * BN;
  const int tid = threadIdx.x;
  const int lane = tid & 63;
  const int wv = tid >> 6;            // 0..3
  const int wr = wv >> 1, wc = wv & 1;
  const int fr = lane & 15;
  const int kb = (lane >> 4) * 8;     // element offset within K-tile

  // per-lane base pointers (row fixed per mi/ni, k advances)
  const float* A0 = Xf + (size_t)v * NB * ND + (size_t)(m0 + wr * 64 + fr) * ND + kb;
  const u16*   B0 = W1T + (size_t)v * NH * ND + (size_t)(n0 + wc * 64 + fr) * ND + kb;

  f32x4 acc[4][4] = {};
  float4 pa0[8], pa1[8];
  bf16x8 pb0[4], pb1[4];

  auto LA = [&](float4* pa, int k) {
#pragma unroll
    for (int mi = 0; mi < 4; ++mi) {
      const float* p = A0 + (size_t)mi * 16 * ND + k;
      pa[2 * mi]     = *(const float4*)p;
      pa[2 * mi + 1] = *(const float4*)(p + 4);
    }
  };
  auto LB = [&](bf16x8* pb, int k) {
#pragma unroll
    for (int ni = 0; ni < 4; ++ni)
      pb[ni] = *(const bf16x8*)(B0 + (size_t)ni * 16 * ND + k);
  };
  auto CMP = [&](const float4* pa, const bf16x8* pb) {
    bf16x8 af[4];
#pragma unroll
    for (int mi = 0; mi < 4; ++mi) af[mi] = cvt8(pa[2 * mi], pa[2 * mi + 1]);
#pragma unroll
    for (int mi = 0; mi < 4; ++mi)
#pragma unroll
      for (int ni = 0; ni < 4; ++ni)
        acc[mi][ni] = __builtin_amdgcn_mfma_f32_16x16x32_bf16(
            af[mi], pb[ni], acc[mi][ni], 0, 0, 0);
  };

  LA(pa0, 0);
  LB(pb0, 0);
  for (int k0 = 0; k0 < ND; k0 += 2 * BK) {
    if (k0 + BK < ND) { LA(pa1, k0 + BK); LB(pb1, k0 + BK); }
    CMP(pa0, pb0);
    if (k0 + 2 * BK < ND) { LA(pa0, k0 + 2 * BK); LB(pb0, k0 + 2 * BK); }
    if (k0 + BK < ND) CMP(pa1, pb1);
  }

  // C/D layout (verified): col = lane&15, row = (lane>>4)*4 + reg
  const int frow = (lane >> 4) * 4;
  const int fcol = lane & 15;
#pragma unroll
  for (int mi = 0; mi < 4; ++mi) {
#pragma unroll
    for (int ni = 0; ni < 4; ++ni) {
      const int n = n0 + wc * 64 + ni * 16 + fcol;
      const float bias = b1[v * NH + n];
#pragma unroll
      for (int j = 0; j < 4; ++j) {
        const int m = m0 + wr * 64 + mi * 16 + frow + j;
        float val = fmaxf(acc[mi][ni][j] + bias, 0.f);
        Hb[(size_t)v * NB * NH + (size_t)m * NH + n] = to_bf16(val);
      }
    }
  }
}

// ------- GEMM2: evidence = softplus(h@W2+b2), N=64. NO-LDS streaming, no bar.
__global__ __launch_bounds__(256) void k_gemm2(const u16* __restrict__ Hb,
                                               const u16* __restrict__ W2T,
                                               const float* __restrict__ b2,
                                               float* __restrict__ out_ev) {
  constexpr int BM = 64, BK = 32;
  const int v = blockIdx.z;
  const int m0 = blockIdx.x * BM;
  const int tid = threadIdx.x;
  const int lane = tid & 63;
  const int wv = tid >> 6;            // wave owns m-slice wv*16
  const int fr = lane & 15;
  const int kb = (lane >> 4) * 8;

  const u16* A0 = Hb + (size_t)v * NB * NH + (size_t)(m0 + wv * 16 + fr) * NH + kb;
  const u16* B0 = W2T + (size_t)v * NCP * NH + (size_t)fr * NH + kb;

  f32x4 acc[4] = {};
  bf16x8 a0, a1, b0_[4], b1_[4];

  auto LA = [&](bf16x8& a, int k) { a = *(const bf16x8*)(A0 + k); };
  auto LB = [&](bf16x8* b, int k) {
#pragma unroll
    for (int ni = 0; ni < 4; ++ni)
      b[ni] = *(const bf16x8*)(B0 + (size_t)ni * 16 * NH + k);
  };
  auto CMP = [&](bf16x8 a, const bf16x8* b) {
#pragma unroll
    for (int ni = 0; ni < 4; ++ni)
      acc[ni] = __builtin_amdgcn_mfma_f32_16x16x32_bf16(a, b[ni], acc[ni], 0, 0, 0);
  };

  LA(a0, 0);
  LB(b0_, 0);
  for (int k0 = 0; k0 < NH; k0 += 2 * BK) {
    if (k0 + BK < NH) { LA(a1, k0 + BK); LB(b1_, k0 + BK); }
    CMP(a0, b0_);
    if (k0 + 2 * BK < NH) { LA(a0, k0 + 2 * BK); LB(b0_, k0 + 2 * BK); }
    if (k0 + BK < NH) CMP(a1, b1_);
  }

  const int frow = (lane >> 4) * 4;
  const int fcol = lane & 15;
#pragma unroll
  for (int ni = 0; ni < 4; ++ni) {
    const int n = ni * 16 + fcol;
    if (n < NC) {
      const float bias = b2[v * NC + n];
#pragma unroll
      for (int j = 0; j < 4; ++j) {
        const int m = m0 + wv * 16 + frow + j;
        float x = acc[ni][j] + bias;
        // stable softplus, matches jax.nn.softplus
        float sp = fmaxf(x, 0.f) + log1pf(expf(-fabsf(x)));
        out_ev[(size_t)v * NB * NC + (size_t)m * NC + n] = sp;
      }
    }
  }
}

// ------------- fused transfer + DS-combine: wave = one batch row b
// (round-7 proven version: high TLP, no LDS, no staging)
__global__ __launch_bounds__(256) void k_tc(const float* __restrict__ evf,
                                            const float* __restrict__ mats,
                                            const int* __restrict__ idx,
                                            float* __restrict__ out_tr,
                                            float* __restrict__ out_ea) {
  const int b = blockIdx.x * 4 + (threadIdx.x >> 6);
  const int lane = threadIdx.x & 63;
  if (b >= NB) return;
  const bool act = lane < NC;
  const float Kf = (float)NC;
  const int ix = idx[b];

  float ta[NV];
#pragma unroll
  for (int v = 0; v < NV; ++v) {
    float acc = 0.f;
    if (act) {
      const float* e = evf + ((size_t)v * NB + b) * NC;
      const float* M = mats + ((size_t)v * NSAMP + ix) * NC * NC;
#pragma unroll
      for (int c = 0; c < NC; ++c)
        acc = fmaf(e[c], M[c * NC + lane], acc);
      out_tr[((size_t)v * NB + b) * NC + lane] = acc;
    }
    ta[v] = act ? acc + 1.0f : 0.0f;
  }

  float alpha = ta[0];
#pragma unroll
  for (int v = 1; v < NV; ++v) {
    float a2 = ta[v];
    float S1 = wsum(act ? alpha : 0.f);
    float S2 = wsum(act ? a2 : 0.f);
    float b1v = act ? (alpha - 1.f) / S1 : 0.f;
    float b2v = act ? (a2 - 1.f) / S2 : 0.f;
    float u1 = Kf / S1, u2 = Kf / S2;
    float sb1 = wsum(b1v);
    float sb2 = wsum(b2v);
    float sb12 = wsum(b1v * b2v);
    float Cconf = sb1 * sb2 - sb12;
    float denom = 1.f - Cconf;
    float b_a = (b1v * b2v + b1v * u2 + b2v * u1) / denom;
    float u_a = u1 * u2 / denom;
    float S_a = Kf / u_a;
    alpha = b_a * S_a + 1.f;  // e_a + 1
  }
  if (act) out_ea[(size_t)b * NC + lane] = alpha - 1.f;
}

// ---------------------------------------------------------------------------
extern "C" void kernel_launch(void* const* d_in, const int* in_sizes, int n_in,
                              void* d_out, int out_size, void* d_ws, size_t ws_size,
                              hipStream_t stream) {
  // Bind inputs BY ELEMENT COUNT (all distinct) — immune to order changes.
  const float *x = nullptr, *W1 = nullptr, *b1 = nullptr, *W2 = nullptr,
              *b2 = nullptr, *mats = nullptr;
  const int* idx = nullptr;
  for (int i = 0; i < n_in; ++i) {
    switch (in_sizes[i]) {
      case 16777216:  x    = (const float*)d_in[i]; break;  // V*B*D
      case 4096:      idx  = (const int*)d_in[i];   break;  // B
      case 2097152:   W1   = (const float*)d_in[i]; break;  // V*D*H
      case 2048:      b1   = (const float*)d_in[i]; break;  // V*H
      case 102400:    W2   = (const float*)d_in[i]; break;  // V*H*C
      case 200:       b2   = (const float*)d_in[i]; break;  // V*C
      case 100000000: mats = (const float*)d_in[i]; break;  // V*S*C*C
      default: break;
    }
  }
  if (!x || !idx || !W1 || !b1 || !W2 || !b2 || !mats) return;

  char* ws = (char*)d_ws;
  // ws layout (bytes): w1t bf16 4194304; w2t bf16 262144; hb bf16 16777216
  u16* w1t = (u16*)(ws + 0);
  u16* w2t = (u16*)(ws + 4194304);
  u16* hb  = (u16*)(ws + 4456448);

  // d_out is FLOAT32: [transferred (V,B,C) | evidence_a (B,C) | evidence (V,B,C)]
  float* out_tr = (float*)d_out;
  float* out_ea = out_tr + (size_t)NV * NB * NC;
  float* out_ev = out_ea + (size_t)NB * NC;

  k_transpose_w1<<<dim3(ND / 32, NH / 32, NV), dim3(32, 8), 0, stream>>>(W1, w1t);
  k_prep_w2<<<(NV * NCP * NH + 255) / 256, 256, 0, stream>>>(W2, w2t);
  k_gemm1<<<dim3(NB / 128, NH / 128, NV), 256, 0, stream>>>(x, w1t, b1, hb);
  k_gemm2<<<dim3(NB / 64, 1, NV), 256, 0, stream>>>(hb, w2t, b2, out_ev);
  k_tc<<<NB / 4, 256, 0, stream>>>(out_ev, mats, idx, out_tr, out_ea);
}

// Round 11
// 100.761 us; speedup vs baseline: 1.4621x; 1.4621x over previous
//
#include <hip/hip_runtime.h>
#include <hip/hip_bf16.h>
#include <math.h>

typedef unsigned short u16;
typedef __attribute__((ext_vector_type(8))) short bf16x8;  // 8 bf16 (4 VGPRs)
typedef __attribute__((ext_vector_type(4))) float f32x4;   // 4 f32 acc

#define DEVI __device__ __forceinline__

constexpr int NV = 4;
constexpr int NB = 4096;
constexpr int ND = 1024;
constexpr int NH = 512;
constexpr int NC = 50;
constexpr int NSAMP = 10000;
constexpr int NCP = 64;  // padded C for MFMA N-dim

DEVI u16 to_bf16(float f) {
  union { float f; unsigned u; } v; v.f = f;
  unsigned r = v.u + 0x7fffu + ((v.u >> 16) & 1u);  // RNE
  return (u16)(r >> 16);
}

// compiler-native cast: emits v_cvt (pairs to v_cvt_pk_bf16_f32), RNE
DEVI u16 cvt_bf16(float f) {
  __hip_bfloat16 h = __float2bfloat16(f);
  return *reinterpret_cast<u16*>(&h);
}

DEVI float wsum(float x) {
#pragma unroll
  for (int m = 32; m > 0; m >>= 1) x += __shfl_xor(x, m, 64);
  return x;
}

#define GLD_LDS16(gsrc, ldst)                                                  \
  __builtin_amdgcn_global_load_lds(                                            \
      (const __attribute__((address_space(1))) void*)(gsrc),                   \
      (__attribute__((address_space(3))) void*)(ldst), 16, 0, 0)

// ---------------- merged prep: W1 transpose (y<16) + W2 pad/cvt (y==16)
// grid (32, 17, 4), block (32, 8)
__global__ __launch_bounds__(256) void k_prep(const float* __restrict__ W1,
                                              const float* __restrict__ W2,
                                              u16* __restrict__ W1T,
                                              u16* __restrict__ W2T) {
  __shared__ float tile[32][33];
  const int v = blockIdx.z;
  const int tx = threadIdx.x, ty = threadIdx.y;  // (32, 8)
  if (blockIdx.y < NH / 32) {
    // ---- W1 (V,D,H) -> (V,H,D) bf16
    const int d0 = blockIdx.x * 32;
    const int h0 = blockIdx.y * 32;
    const float* src = W1 + (size_t)v * ND * NH;
    u16* dst = W1T + (size_t)v * NH * ND;
#pragma unroll
    for (int j = 0; j < 32; j += 8)
      tile[ty + j][tx] = src[(size_t)(d0 + ty + j) * NH + h0 + tx];
    __syncthreads();
#pragma unroll
    for (int j = 0; j < 32; j += 8)
      dst[(size_t)(h0 + ty + j) * ND + d0 + tx] = to_bf16(tile[tx][ty + j]);
  } else {
    // ---- W2 (V,H,C) -> (V,64,H) bf16 zero-pad; 32 blocks x 256 thr x 4 elems
    const int tid = ty * 32 + tx;
#pragma unroll
    for (int i = 0; i < 4; ++i) {
      int e = blockIdx.x * 1024 + i * 256 + tid;  // 0..32767 = c*NH + h
      int h = e % NH;
      int c = e / NH;  // 0..63
      float val = (c < NC) ? W2[((size_t)v * NH + h) * NC + c] : 0.f;
      W2T[(size_t)v * NCP * NH + e] = to_bf16(val);
    }
  }
}

// --------------------------------------------------- GEMM1: h=relu(x@W1+b1)
// r7 structure (single buffer, 2 barriers/K-step, T14 A-reg prefetch) with
// BK=64: halves barrier count; LDS 32 KB is free (grid-limited 2 blocks/CU).
__global__ __launch_bounds__(256) void k_gemm1(const float* __restrict__ Xf,
                                               const u16* __restrict__ W1T,
                                               const float* __restrict__ b1,
                                               u16* __restrict__ Hb) {
  constexpr int BM = 128, BN = 128, BK = 64;
  const int v = blockIdx.z;
  const int m0 = blockIdx.x * BM;
  const int n0 = blockIdx.y * BN;
  __shared__ u16 As[BM][BK];  // 16 KB
  __shared__ u16 Bs[BN][BK];  // 16 KB
  const float* Ag = Xf + (size_t)v * NB * ND + (size_t)m0 * ND;
  const u16* Bg = W1T + (size_t)v * NH * ND + (size_t)n0 * ND;
  const int tid = threadIdx.x;
  const int lane = tid & 63;
  const int wv = tid >> 6;            // 0..3
  const int wr = wv >> 1, wc = wv & 1;
  const int rA = tid >> 1;            // 0..127 (1 row / thread)
  const int cA = (tid & 1) * 32;      // 32 f32 per thread

  f32x4 acc[4][4] = {};

  // prologue: prefetch A-tile k0=0 into registers (8 x float4 = 32 f32)
  float4 pa[8];
#pragma unroll
  for (int i = 0; i < 8; ++i)
    pa[i] = *(const float4*)(Ag + (size_t)rA * ND + cA + i * 4);

  for (int k0 = 0; k0 < ND; k0 += BK) {
    __syncthreads();  // previous iter's LDS reads done before overwrite
    // A: registers (already arrived) -> cvt -> LDS
#pragma unroll
    for (int i = 0; i < 8; ++i) {
      ushort4 u;
      u.x = cvt_bf16(pa[i].x); u.y = cvt_bf16(pa[i].y);
      u.z = cvt_bf16(pa[i].z); u.w = cvt_bf16(pa[i].w);
      *(ushort4*)&As[rA][cA + i * 4] = u;
    }
    // B: async global->LDS, 4 x 16B per thread; lds addr = slot*16 (linear)
#pragma unroll
    for (int i = 0; i < 4; ++i) {
      int s = tid + i * 256;  // 0..1023
      GLD_LDS16(Bg + (size_t)(s >> 3) * ND + k0 + (s & 7) * 8,
                &Bs[s >> 3][(s & 7) * 8]);
    }
    __syncthreads();  // drains lgkm (ds_write) + vmcnt (gld_lds)

    // T14: issue NEXT tile's A loads now; latency hides under MFMA phase.
    if (k0 + BK < ND) {
#pragma unroll
      for (int i = 0; i < 8; ++i)
        pa[i] = *(const float4*)(Ag + (size_t)rA * ND + k0 + BK + cA + i * 4);
    }

    const int fr = lane & 15;
    const int kb = (lane >> 4) * 8;
    // two k-substeps of 32, same order as two BK=32 steps -> bit-identical
#pragma unroll
    for (int ks = 0; ks < 2; ++ks) {
      const int ko = ks * 32 + kb;
      bf16x8 af[4], bf[4];
#pragma unroll
      for (int mi = 0; mi < 4; ++mi)
        af[mi] = *(const bf16x8*)&As[wr * 64 + mi * 16 + fr][ko];
#pragma unroll
      for (int ni = 0; ni < 4; ++ni)
        bf[ni] = *(const bf16x8*)&Bs[wc * 64 + ni * 16 + fr][ko];
#pragma unroll
      for (int mi = 0; mi < 4; ++mi)
#pragma unroll
        for (int ni = 0; ni < 4; ++ni)
          acc[mi][ni] = __builtin_amdgcn_mfma_f32_16x16x32_bf16(
              af[mi], bf[ni], acc[mi][ni], 0, 0, 0);
    }
  }

  // C/D layout (verified): col = lane&15, row = (lane>>4)*4 + reg
  const int frow = (lane >> 4) * 4;
  const int fcol = lane & 15;
#pragma unroll
  for (int mi = 0; mi < 4; ++mi) {
#pragma unroll
    for (int ni = 0; ni < 4; ++ni) {
      const int n = n0 + wc * 64 + ni * 16 + fcol;
      const float bias = b1[v * NH + n];
#pragma unroll
      for (int j = 0; j < 4; ++j) {
        const int m = m0 + wr * 64 + mi * 16 + frow + j;
        float val = fmaxf(acc[mi][ni][j] + bias, 0.f);
        Hb[(size_t)v * NB * NH + (size_t)m * NH + n] = to_bf16(val);
      }
    }
  }
}

// -------- GEMM2: evidence = softplus(h@W2+b2), N=64 (round-7 structure)
__global__ __launch_bounds__(256) void k_gemm2(const u16* __restrict__ Hb,
                                               const u16* __restrict__ W2T,
                                               const float* __restrict__ b2,
                                               float* __restrict__ out_ev) {
  constexpr int BM = 64, BK = 32;
  const int v = blockIdx.z;
  const int m0 = blockIdx.x * BM;
  __shared__ u16 As[BM][BK];    // 4 KB
  __shared__ u16 Bs[NCP][BK];   // 4 KB
  const u16* Ag = Hb + (size_t)v * NB * NH + (size_t)m0 * NH;
  const u16* Bg = W2T + (size_t)v * NCP * NH;
  const int tid = threadIdx.x;
  const int lane = tid & 63;
  const int wv = tid >> 6;
  const int r = tid >> 2;
  const int c8 = (tid & 3) * 8;

  f32x4 acc[4] = {};

  for (int k0 = 0; k0 < NH; k0 += BK) {
    __syncthreads();
    GLD_LDS16(Ag + (size_t)r * NH + k0 + c8, &As[r][c8]);
    GLD_LDS16(Bg + (size_t)r * NH + k0 + c8, &Bs[r][c8]);
    __syncthreads();

    const int fr = lane & 15;
    const int kb = (lane >> 4) * 8;
    bf16x8 af = *(const bf16x8*)&As[wv * 16 + fr][kb];
#pragma unroll
    for (int ni = 0; ni < 4; ++ni) {
      bf16x8 bf = *(const bf16x8*)&Bs[ni * 16 + fr][kb];
      acc[ni] = __builtin_amdgcn_mfma_f32_16x16x32_bf16(af, bf, acc[ni], 0, 0, 0);
    }
  }

  const int frow = (lane >> 4) * 4;
  const int fcol = lane & 15;
#pragma unroll
  for (int ni = 0; ni < 4; ++ni) {
    const int n = ni * 16 + fcol;
    if (n < NC) {
      const float bias = b2[v * NC + n];
#pragma unroll
      for (int j = 0; j < 4; ++j) {
        const int m = m0 + wv * 16 + frow + j;
        float x = acc[ni][j] + bias;
        // stable softplus, matches jax.nn.softplus
        float sp = fmaxf(x, 0.f) + log1pf(expf(-fabsf(x)));
        out_ev[(size_t)v * NB * NC + (size_t)m * NC + n] = sp;
      }
    }
  }
}

// ------------- fused transfer + DS-combine: wave = one batch row b
// (round-7 proven version: high TLP, no LDS, no staging)
__global__ __launch_bounds__(256) void k_tc(const float* __restrict__ evf,
                                            const float* __restrict__ mats,
                                            const int* __restrict__ idx,
                                            float* __restrict__ out_tr,
                                            float* __restrict__ out_ea) {
  const int b = blockIdx.x * 4 + (threadIdx.x >> 6);
  const int lane = threadIdx.x & 63;
  if (b >= NB) return;
  const bool act = lane < NC;
  const float Kf = (float)NC;
  const int ix = idx[b];

  float ta[NV];
#pragma unroll
  for (int v = 0; v < NV; ++v) {
    float acc = 0.f;
    if (act) {
      const float* e = evf + ((size_t)v * NB + b) * NC;
      const float* M = mats + ((size_t)v * NSAMP + ix) * NC * NC;
#pragma unroll
      for (int c = 0; c < NC; ++c)
        acc = fmaf(e[c], M[c * NC + lane], acc);
      out_tr[((size_t)v * NB + b) * NC + lane] = acc;
    }
    ta[v] = act ? acc + 1.0f : 0.0f;
  }

  float alpha = ta[0];
#pragma unroll
  for (int v = 1; v < NV; ++v) {
    float a2 = ta[v];
    float S1 = wsum(act ? alpha : 0.f);
    float S2 = wsum(act ? a2 : 0.f);
    float b1v = act ? (alpha - 1.f) / S1 : 0.f;
    float b2v = act ? (a2 - 1.f) / S2 : 0.f;
    float u1 = Kf / S1, u2 = Kf / S2;
    float sb1 = wsum(b1v);
    float sb2 = wsum(b2v);
    float sb12 = wsum(b1v * b2v);
    float Cconf = sb1 * sb2 - sb12;
    float denom = 1.f - Cconf;
    float b_a = (b1v * b2v + b1v * u2 + b2v * u1) / denom;
    float u_a = u1 * u2 / denom;
    float S_a = Kf / u_a;
    alpha = b_a * S_a + 1.f;  // e_a + 1
  }
  if (act) out_ea[(size_t)b * NC + lane] = alpha - 1.f;
}

// ---------------------------------------------------------------------------
extern "C" void kernel_launch(void* const* d_in, const int* in_sizes, int n_in,
                              void* d_out, int out_size, void* d_ws, size_t ws_size,
                              hipStream_t stream) {
  // Bind inputs BY ELEMENT COUNT (all distinct) — immune to order changes.
  const float *x = nullptr, *W1 = nullptr, *b1 = nullptr, *W2 = nullptr,
              *b2 = nullptr, *mats = nullptr;
  const int* idx = nullptr;
  for (int i = 0; i < n_in; ++i) {
    switch (in_sizes[i]) {
      case 16777216:  x    = (const float*)d_in[i]; break;  // V*B*D
      case 4096:      idx  = (const int*)d_in[i];   break;  // B
      case 2097152:   W1   = (const float*)d_in[i]; break;  // V*D*H
      case 2048:      b1   = (const float*)d_in[i]; break;  // V*H
      case 102400:    W2   = (const float*)d_in[i]; break;  // V*H*C
      case 200:       b2   = (const float*)d_in[i]; break;  // V*C
      case 100000000: mats = (const float*)d_in[i]; break;  // V*S*C*C
      default: break;
    }
  }
  if (!x || !idx || !W1 || !b1 || !W2 || !b2 || !mats) return;

  char* ws = (char*)d_ws;
  // ws layout (bytes): w1t bf16 4194304; w2t bf16 262144; hb bf16 16777216
  u16* w1t = (u16*)(ws + 0);
  u16* w2t = (u16*)(ws + 4194304);
  u16* hb  = (u16*)(ws + 4456448);

  // d_out is FLOAT32: [transferred (V,B,C) | evidence_a (B,C) | evidence (V,B,C)]
  float* out_tr = (float*)d_out;
  float* out_ea = out_tr + (size_t)NV * NB * NC;
  float* out_ev = out_ea + (size_t)NB * NC;

  k_prep<<<dim3(32, NH / 32 + 1, NV), dim3(32, 8), 0, stream>>>(W1, W2, w1t, w2t);
  k_gemm1<<<dim3(NB / 128, NH / 128, NV), 256, 0, stream>>>(x, w1t, b1, hb);
  k_gemm2<<<dim3(NB / 64, 1, NV), 256, 0, stream>>>(hb, w2t, b2, out_ev);
  k_tc<<<NB / 4, 256, 0, stream>>>(out_ev, mats, idx, out_tr, out_ea);
}

// Round 13
// 89.555 us; speedup vs baseline: 1.6450x; 1.1251x over previous
//
#include <hip/hip_runtime.h>
#include <hip/hip_bf16.h>
#include <math.h>

typedef unsigned short u16;
typedef __attribute__((ext_vector_type(8))) short bf16x8;  // 8 bf16 (4 VGPRs)
typedef __attribute__((ext_vector_type(4))) float f32x4;   // 4 f32 acc

#define DEVI __device__ __forceinline__

constexpr int NV = 4;
constexpr int NB = 4096;
constexpr int ND = 1024;
constexpr int NH = 512;
constexpr int NC = 50;
constexpr int NSAMP = 10000;
constexpr int NCP = 64;  // padded C for MFMA N-dim

DEVI u16 to_bf16(float f) {
  union { float f; unsigned u; } v; v.f = f;
  unsigned r = v.u + 0x7fffu + ((v.u >> 16) & 1u);  // RNE
  return (u16)(r >> 16);
}

// compiler-native cast: emits v_cvt (pairs to v_cvt_pk_bf16_f32), RNE
DEVI u16 cvt_bf16(float f) {
  __hip_bfloat16 h = __float2bfloat16(f);
  return *reinterpret_cast<u16*>(&h);
}

DEVI float wsum(float x) {
#pragma unroll
  for (int m = 32; m > 0; m >>= 1) x += __shfl_xor(x, m, 64);
  return x;
}

#define GLD_LDS16(gsrc, ldst)                                                  \
  __builtin_amdgcn_global_load_lds(                                            \
      (const __attribute__((address_space(1))) void*)(gsrc),                   \
      (__attribute__((address_space(3))) void*)(ldst), 16, 0, 0)

// ---------------- merged prep: W1 transpose (y<16) + W2 pad/cvt (y==16)
// grid (32, 17, 4), block (32, 8)
__global__ __launch_bounds__(256) void k_prep(const float* __restrict__ W1,
                                              const float* __restrict__ W2,
                                              u16* __restrict__ W1T,
                                              u16* __restrict__ W2T) {
  __shared__ float tile[32][33];
  const int v = blockIdx.z;
  const int tx = threadIdx.x, ty = threadIdx.y;  // (32, 8)
  if (blockIdx.y < NH / 32) {
    // ---- W1 (V,D,H) -> (V,H,D) bf16
    const int d0 = blockIdx.x * 32;
    const int h0 = blockIdx.y * 32;
    const float* src = W1 + (size_t)v * ND * NH;
    u16* dst = W1T + (size_t)v * NH * ND;
#pragma unroll
    for (int j = 0; j < 32; j += 8)
      tile[ty + j][tx] = src[(size_t)(d0 + ty + j) * NH + h0 + tx];
    __syncthreads();
#pragma unroll
    for (int j = 0; j < 32; j += 8)
      dst[(size_t)(h0 + ty + j) * ND + d0 + tx] = to_bf16(tile[tx][ty + j]);
  } else {
    // ---- W2 (V,H,C) -> (V,64,H) bf16 zero-pad; 32 blocks x 256 thr x 4 elems
    const int tid = ty * 32 + tx;
#pragma unroll
    for (int i = 0; i < 4; ++i) {
      int e = blockIdx.x * 1024 + i * 256 + tid;  // 0..32767 = c*NH + h
      int h = e % NH;
      int c = e / NH;  // 0..63
      float val = (c < NC) ? W2[((size_t)v * NH + h) * NC + c] : 0.f;
      W2T[(size_t)v * NCP * NH + e] = to_bf16(val);
    }
  }
}

// --------------------------------------------------- GEMM1: h=relu(x@W1+b1)
// r7 schedule (single buffer, 2 barriers/K-step, BK=32, T14 A-reg prefetch)
// widened to BN=256 / 512 threads / 8 waves: halves x re-read traffic.
__global__ __launch_bounds__(512) void k_gemm1(const float* __restrict__ Xf,
                                               const u16* __restrict__ W1T,
                                               const float* __restrict__ b1,
                                               u16* __restrict__ Hb) {
  constexpr int BM = 128, BN = 256, BK = 32;
  const int v = blockIdx.z;
  const int m0 = blockIdx.x * BM;
  const int n0 = blockIdx.y * BN;
  __shared__ u16 As[BM][BK];  // 8 KB
  __shared__ u16 Bs[BN][BK];  // 16 KB
  const float* Ag = Xf + (size_t)v * NB * ND + (size_t)m0 * ND;
  const u16* Bg = W1T + (size_t)v * NH * ND + (size_t)n0 * ND;
  const int tid = threadIdx.x;
  const int lane = tid & 63;
  const int wv = tid >> 6;             // 0..7
  const int wr = wv >> 2, wc = wv & 3; // wave sub-tile (2 x 4 of 64x64)
  const int rA = tid >> 2;             // 0..127 (1 row / thread)
  const int cA = (tid & 3) * 8;        // 8 f32 per thread

  f32x4 acc[4][4] = {};

  // prologue: prefetch A-tile k0=0 into registers (2 x float4 = 8 f32)
  float4 pa0 = *(const float4*)(Ag + (size_t)rA * ND + cA);
  float4 pa1 = *(const float4*)(Ag + (size_t)rA * ND + cA + 4);

  for (int k0 = 0; k0 < ND; k0 += BK) {
    __syncthreads();  // previous iter's LDS reads done before overwrite
    // A: registers (already arrived) -> cvt -> LDS (ds_write, per-lane ok)
    {
      ushort4 u0, u1;
      u0.x = cvt_bf16(pa0.x); u0.y = cvt_bf16(pa0.y);
      u0.z = cvt_bf16(pa0.z); u0.w = cvt_bf16(pa0.w);
      u1.x = cvt_bf16(pa1.x); u1.y = cvt_bf16(pa1.y);
      u1.z = cvt_bf16(pa1.z); u1.w = cvt_bf16(pa1.w);
      *(ushort4*)&As[rA][cA]     = u0;
      *(ushort4*)&As[rA][cA + 4] = u1;
    }
    // B: async global->LDS, 2 x 16B per thread, slot pattern keeps the
    // per-wave LDS byte address linear in tid (gld_lds HW requirement):
    // slot s -> LDS byte s*16 -> Bs[s>>2][(s&3)*8]; 1024 slots = 8192 elems.
#pragma unroll
    for (int i = 0; i < 2; ++i) {
      int s = tid + i * 512;  // 0..1023
      GLD_LDS16(Bg + (size_t)(s >> 2) * ND + k0 + (s & 3) * 8,
                &Bs[s >> 2][(s & 3) * 8]);
    }
    __syncthreads();  // drains lgkm (ds_write) + vmcnt (gld_lds)

    // T14: issue NEXT tile's A loads now; latency hides under MFMA phase.
    if (k0 + BK < ND) {
      pa0 = *(const float4*)(Ag + (size_t)rA * ND + k0 + BK + cA);
      pa1 = *(const float4*)(Ag + (size_t)rA * ND + k0 + BK + cA + 4);
    }

    const int fr = lane & 15;
    const int kb = (lane >> 4) * 8;
    bf16x8 af[4], bf[4];
#pragma unroll
    for (int mi = 0; mi < 4; ++mi)
      af[mi] = *(const bf16x8*)&As[wr * 64 + mi * 16 + fr][kb];
#pragma unroll
    for (int ni = 0; ni < 4; ++ni)
      bf[ni] = *(const bf16x8*)&Bs[wc * 64 + ni * 16 + fr][kb];
#pragma unroll
    for (int mi = 0; mi < 4; ++mi)
#pragma unroll
      for (int ni = 0; ni < 4; ++ni)
        acc[mi][ni] = __builtin_amdgcn_mfma_f32_16x16x32_bf16(
            af[mi], bf[ni], acc[mi][ni], 0, 0, 0);
  }

  // C/D layout (verified): col = lane&15, row = (lane>>4)*4 + reg
  const int frow = (lane >> 4) * 4;
  const int fcol = lane & 15;
#pragma unroll
  for (int mi = 0; mi < 4; ++mi) {
#pragma unroll
    for (int ni = 0; ni < 4; ++ni) {
      const int n = n0 + wc * 64 + ni * 16 + fcol;
      const float bias = b1[v * NH + n];
#pragma unroll
      for (int j = 0; j < 4; ++j) {
        const int m = m0 + wr * 64 + mi * 16 + frow + j;
        float val = fmaxf(acc[mi][ni][j] + bias, 0.f);
        Hb[(size_t)v * NB * NH + (size_t)m * NH + n] = to_bf16(val);
      }
    }
  }
}

// -------- GEMM2: evidence = softplus(h@W2+b2), N=64 (round-7 structure)
__global__ __launch_bounds__(256) void k_gemm2(const u16* __restrict__ Hb,
                                               const u16* __restrict__ W2T,
                                               const float* __restrict__ b2,
                                               float* __restrict__ out_ev) {
  constexpr int BM = 64, BK = 32;
  const int v = blockIdx.z;
  const int m0 = blockIdx.x * BM;
  __shared__ u16 As[BM][BK];    // 4 KB
  __shared__ u16 Bs[NCP][BK];   // 4 KB
  const u16* Ag = Hb + (size_t)v * NB * NH + (size_t)m0 * NH;
  const u16* Bg = W2T + (size_t)v * NCP * NH;
  const int tid = threadIdx.x;
  const int lane = tid & 63;
  const int wv = tid >> 6;
  const int r = tid >> 2;
  const int c8 = (tid & 3) * 8;

  f32x4 acc[4] = {};

  for (int k0 = 0; k0 < NH; k0 += BK) {
    __syncthreads();
    GLD_LDS16(Ag + (size_t)r * NH + k0 + c8, &As[r][c8]);
    GLD_LDS16(Bg + (size_t)r * NH + k0 + c8, &Bs[r][c8]);
    __syncthreads();

    const int fr = lane & 15;
    const int kb = (lane >> 4) * 8;
    bf16x8 af = *(const bf16x8*)&As[wv * 16 + fr][kb];
#pragma unroll
    for (int ni = 0; ni < 4; ++ni) {
      bf16x8 bf = *(const bf16x8*)&Bs[ni * 16 + fr][kb];
      acc[ni] = __builtin_amdgcn_mfma_f32_16x16x32_bf16(af, bf, acc[ni], 0, 0, 0);
    }
  }

  const int frow = (lane >> 4) * 4;
  const int fcol = lane & 15;
#pragma unroll
  for (int ni = 0; ni < 4; ++ni) {
    const int n = ni * 16 + fcol;
    if (n < NC) {
      const float bias = b2[v * NC + n];
#pragma unroll
      for (int j = 0; j < 4; ++j) {
        const int m = m0 + wv * 16 + frow + j;
        float x = acc[ni][j] + bias;
        // stable softplus, matches jax.nn.softplus
        float sp = fmaxf(x, 0.f) + log1pf(expf(-fabsf(x)));
        out_ev[(size_t)v * NB * NC + (size_t)m * NC + n] = sp;
      }
    }
  }
}

// ------------- fused transfer + DS-combine: wave = one batch row b
// (round-7 proven version: high TLP, no LDS, no staging)
__global__ __launch_bounds__(256) void k_tc(const float* __restrict__ evf,
                                            const float* __restrict__ mats,
                                            const int* __restrict__ idx,
                                            float* __restrict__ out_tr,
                                            float* __restrict__ out_ea) {
  const int b = blockIdx.x * 4 + (threadIdx.x >> 6);
  const int lane = threadIdx.x & 63;
  if (b >= NB) return;
  const bool act = lane < NC;
  const float Kf = (float)NC;
  const int ix = idx[b];

  float ta[NV];
#pragma unroll
  for (int v = 0; v < NV; ++v) {
    float acc = 0.f;
    if (act) {
      const float* e = evf + ((size_t)v * NB + b) * NC;
      const float* M = mats + ((size_t)v * NSAMP + ix) * NC * NC;
#pragma unroll
      for (int c = 0; c < NC; ++c)
        acc = fmaf(e[c], M[c * NC + lane], acc);
      out_tr[((size_t)v * NB + b) * NC + lane] = acc;
    }
    ta[v] = act ? acc + 1.0f : 0.0f;
  }

  float alpha = ta[0];
#pragma unroll
  for (int v = 1; v < NV; ++v) {
    float a2 = ta[v];
    float S1 = wsum(act ? alpha : 0.f);
    float S2 = wsum(act ? a2 : 0.f);
    float b1v = act ? (alpha - 1.f) / S1 : 0.f;
    float b2v = act ? (a2 - 1.f) / S2 : 0.f;
    float u1 = Kf / S1, u2 = Kf / S2;
    float sb1 = wsum(b1v);
    float sb2 = wsum(b2v);
    float sb12 = wsum(b1v * b2v);
    float Cconf = sb1 * sb2 - sb12;
    float denom = 1.f - Cconf;
    float b_a = (b1v * b2v + b1v * u2 + b2v * u1) / denom;
    float u_a = u1 * u2 / denom;
    float S_a = Kf / u_a;
    alpha = b_a * S_a + 1.f;  // e_a + 1
  }
  if (act) out_ea[(size_t)b * NC + lane] = alpha - 1.f;
}

// ---------------------------------------------------------------------------
extern "C" void kernel_launch(void* const* d_in, const int* in_sizes, int n_in,
                              void* d_out, int out_size, void* d_ws, size_t ws_size,
                              hipStream_t stream) {
  // Bind inputs BY ELEMENT COUNT (all distinct) — immune to order changes.
  const float *x = nullptr, *W1 = nullptr, *b1 = nullptr, *W2 = nullptr,
              *b2 = nullptr, *mats = nullptr;
  const int* idx = nullptr;
  for (int i = 0; i < n_in; ++i) {
    switch (in_sizes[i]) {
      case 16777216:  x    = (const float*)d_in[i]; break;  // V*B*D
      case 4096:      idx  = (const int*)d_in[i];   break;  // B
      case 2097152:   W1   = (const float*)d_in[i]; break;  // V*D*H
      case 2048:      b1   = (const float*)d_in[i]; break;  // V*H
      case 102400:    W2   = (const float*)d_in[i]; break;  // V*H*C
      case 200:       b2   = (const float*)d_in[i]; break;  // V*C
      case 100000000: mats = (const float*)d_in[i]; break;  // V*S*C*C
      default: break;
    }
  }
  if (!x || !idx || !W1 || !b1 || !W2 || !b2 || !mats) return;

  char* ws = (char*)d_ws;
  // ws layout (bytes): w1t bf16 4194304; w2t bf16 262144; hb bf16 16777216
  u16* w1t = (u16*)(ws + 0);
  u16* w2t = (u16*)(ws + 4194304);
  u16* hb  = (u16*)(ws + 4456448);

  // d_out is FLOAT32: [transferred (V,B,C) | evidence_a (B,C) | evidence (V,B,C)]
  float* out_tr = (float*)d_out;
  float* out_ea = out_tr + (size_t)NV * NB * NC;
  float* out_ev = out_ea + (size_t)NB * NC;

  k_prep<<<dim3(32, NH / 32 + 1, NV), dim3(32, 8), 0, stream>>>(W1, W2, w1t, w2t);
  k_gemm1<<<dim3(NB / 128, NH / 256, NV), 512, 0, stream>>>(x, w1t, b1, hb);
  k_gemm2<<<dim3(NB / 64, 1, NV), 256, 0, stream>>>(hb, w2t, b2, out_ev);
  k_tc<<<NB / 4, 256, 0, stream>>>(out_ev, mats, idx, out_tr, out_ea);
}